// Round 7
// baseline (968.634 us; speedup 1.0000x reference)
//
#include <hip/hip_runtime.h>

// GRU reward model, swapped-operand MFMA + gi-pipelined formulation.
//   B=1024 seqs, T=1024 steps, Din=36 (obs32+act4+bias), H=64, gates 3H=192.
//   64 blocks x 256 threads (4 waves); block owns 16 sequences.
//   A = weight tiles (units in M), B = [x|h] (seqs in N); C = [units x seqs]:
//   lane owns 4 consecutive units of one seq.
//   KEY CHANGE vs round 6: gi(t) = x(t) x W_ih^T is computed TWO STEPS AHEAD
//   into a named f32x4 register ring (x fragments prefetched 4 steps ahead),
//   so the per-step critical chain is only:
//     barrier -> ds_read h -> 2 dependent h-MFMAs -> gates -> ds_write -> barrier
//   and the 6 x-MFMAs issue inside the ds_read latency window.
//   One s_barrier + lgkmcnt(0) per step; vmcnt never drains across barriers.

#define BB 1024
#define TT 1024
#define DOBS 32
#define DACT 4
#define HH 64

typedef __attribute__((ext_vector_type(8))) short short8;
typedef __attribute__((ext_vector_type(4))) float f32x4;

#define MFMA(A, B, C) __builtin_amdgcn_mfma_f32_16x16x32_bf16((A), (B), (C), 0, 0, 0)

static __device__ __forceinline__ unsigned short f2bf(float f) {
    unsigned u = __float_as_uint(f);
    u += 0x7fffu + ((u >> 16) & 1u);   // RNE
    return (unsigned short)(u >> 16);
}
static __device__ __forceinline__ float frcp(float x) { return __builtin_amdgcn_rcpf(x); }
static __device__ __forceinline__ unsigned cvt_pk(float lo, float hi) {
    unsigned r;
    asm("v_cvt_pk_bf16_f32 %0, %1, %2" : "=v"(r) : "v"(lo), "v"(hi));
    return r;
}

#define L2E 1.442695040888963f

// LOADX: fetch x(t) B-fragments for this lane (seq = c, k = 8q+i / 32+8q+i)
#define LOADX(XO, XA, T)                                                       \
  {                                                                            \
    const int tc_ = (T) < TT ? (T) : TT - 1;                                   \
    const float* op_ = po + (size_t)tc_ * DOBS + 8 * q;                        \
    float4 a_ = *(const float4*)op_, b_ = *(const float4*)(op_ + 4);           \
    short8 f_;                                                                 \
    f_[0]=f2bf(a_.x); f_[1]=f2bf(a_.y); f_[2]=f2bf(a_.z); f_[3]=f2bf(a_.w);    \
    f_[4]=f2bf(b_.x); f_[5]=f2bf(b_.y); f_[6]=f2bf(b_.z); f_[7]=f2bf(b_.w);    \
    XO = f_;                                                                   \
    if (q == 0) {                                                              \
      float4 av_ = *(const float4*)(pa + (size_t)tc_ * DACT);                  \
      short8 g_;                                                               \
      g_[0]=f2bf(av_.x); g_[1]=f2bf(av_.y); g_[2]=f2bf(av_.z);                 \
      g_[3]=f2bf(av_.w); g_[4]=(short)0x3f80; g_[5]=0; g_[6]=0; g_[7]=0;       \
      XA = g_;                                                                 \
    } else XA = zero8;                                                         \
  }

// STEP: PH is the LITERAL hbuf phase (0 for even t, 1 for odd t).
// CR_/CZ_/CN_ are this parity's gi ring slots (named regs, never runtime-indexed).
#define STEP(XO, XA, CR_, CZ_, CN_, PH, T)                                     \
  {                                                                            \
    short8 Ah0 = *(const short8*)((const char*)hbuf[PH] + rdaddr0);            \
    short8 Ah1 = *(const short8*)((const char*)hbuf[PH] + rdaddr1);            \
    f32x4 cr_ = CR_, cz_ = CZ_, cni_ = CN_;      /* gi(T), computed at T-2 */  \
    CR_ = MFMA(AX[0][1], XA, MFMA(AX[0][0], XO, zf));   /* gi(T+2): off-chain */ \
    CZ_ = MFMA(AX[1][1], XA, MFMA(AX[1][0], XO, zf));                          \
    CN_ = MFMA(AX[2][1], XA, MFMA(AX[2][0], XO, zf));                          \
    LOADX(XO, XA, (T) + 4)                       /* refill x ring (t+4) */     \
    f32x4 Cr  = MFMA(AH[0][1], Ah1, MFMA(AH[0][0], Ah0, cr_));                 \
    f32x4 Cz  = MFMA(AH[1][1], Ah1, MFMA(AH[1][0], Ah0, cz_));                 \
    f32x4 Cnh = MFMA(AH[2][1], Ah1, MFMA(AH[2][0], Ah0, bhn4));                \
    f32x4 Crw = zf;                                                            \
    if (w == 3) Crw = MFMA(AR[1], Ah1, MFMA(AR[0], Ah0, zf));                  \
    _Pragma("unroll")                                                          \
    for (int reg = 0; reg < 4; ++reg) {                                        \
      float rr   = frcp(1.0f + __builtin_amdgcn_exp2f(Cr[reg] * -L2E));        \
      float zz   = frcp(1.0f + __builtin_amdgcn_exp2f(Cz[reg] * -L2E));        \
      float npre = __builtin_fmaf(rr, Cnh[reg], cni_[reg]);                    \
      float nn   = 1.0f - 2.0f * frcp(__builtin_amdgcn_exp2f(npre * (2.0f * L2E)) + 1.0f); \
      hold[reg]  = __builtin_fmaf(zz, hold[reg] - nn, nn);                     \
    }                                                                          \
    unsigned pk0 = cvt_pk(hold[0], hold[1]);                                   \
    unsigned pk1 = cvt_pk(hold[2], hold[3]);                                   \
    *(uint2*)((char*)hbuf[PH ^ 1] + wraddr) = make_uint2(pk0, pk1);            \
    if (w == 3 && q == 0 && (T) > 0)                                           \
      rew[(size_t)(bid * 16 + c) * TT + (T) - 1] = Crw[0] + brr;               \
    asm volatile("s_waitcnt lgkmcnt(0)" ::: "memory");                         \
    __builtin_amdgcn_s_barrier();                                              \
    asm volatile("" ::: "memory");                                             \
  }

__global__ __launch_bounds__(256, 1)
void gru_fused(const float* __restrict__ obs, const float* __restrict__ act,
               const float* __restrict__ W_ih, const float* __restrict__ b_ih,
               const float* __restrict__ W_hh, const float* __restrict__ b_hh,
               const float* __restrict__ W_r, const float* __restrict__ b_r,
               float* __restrict__ out)
{
    const int tid = threadIdx.x;
    const int w = tid >> 6, l = tid & 63, c = l & 15, q = l >> 4;
    const int bid = blockIdx.x;
    const int u0 = 16 * w + 4 * q;           // first of this lane's 4 units

    __shared__ __align__(16) unsigned short hbuf[2][16 * 64];  // [seq][unit] bf16

    // ---- weight A-fragments ----
    short8 AX[3][2], AH[3][2];
#pragma unroll
    for (int m = 0; m < 3; ++m) {
        const int j = w + 4 * m;             // tile: w=r, w+4=z, w+8=n
        const int g = 16 * j + c;            // gate row (A-row = c)
        {   // x-weights, k 0..31
            const float* wp = W_ih + (size_t)g * 36 + 8 * q;
            float4 a = *(const float4*)wp, b = *(const float4*)(wp + 4);
            short8 f;
            f[0]=f2bf(a.x); f[1]=f2bf(a.y); f[2]=f2bf(a.z); f[3]=f2bf(a.w);
            f[4]=f2bf(b.x); f[5]=f2bf(b.y); f[6]=f2bf(b.z); f[7]=f2bf(b.w);
            AX[m][0] = f;
        }
        {   // x-weights, k 32..63 (act + bias slot + zeros)
            short8 f;
#pragma unroll
            for (int i = 0; i < 8; ++i) {
                int k = 32 + 8 * q + i;
                float v = 0.f;
                if (k < 36)       v = W_ih[(size_t)g * 36 + k];
                else if (k == 36) v = b_ih[g] + (g < 128 ? b_hh[g] : 0.f);
                f[i] = f2bf(v);
            }
            AX[m][1] = f;
        }
#pragma unroll
        for (int kk = 0; kk < 2; ++kk) {     // h-weights
            const float* wp = W_hh + (size_t)g * HH + 32 * kk + 8 * q;
            float4 a = *(const float4*)wp, b = *(const float4*)(wp + 4);
            short8 f;
            f[0]=f2bf(a.x); f[1]=f2bf(a.y); f[2]=f2bf(a.z); f[3]=f2bf(a.w);
            f[4]=f2bf(b.x); f[5]=f2bf(b.y); f[6]=f2bf(b.z); f[7]=f2bf(b.w);
            AH[m][kk] = f;
        }
    }
    short8 AR[2];                            // reward tile: A-row 0 = W_r
#pragma unroll
    for (int kk = 0; kk < 2; ++kk) {
        short8 f;
#pragma unroll
        for (int i = 0; i < 8; ++i) {
            int k = 32 * kk + 8 * q + i;
            f[i] = (c == 0) ? (short)f2bf(W_r[k]) : (short)0;
        }
        AR[kk] = f;
    }

    f32x4 bhn4;                              // Cnh C-init: b_hh[n] for lane's units
#pragma unroll
    for (int reg = 0; reg < 4; ++reg) bhn4[reg] = b_hh[128 + u0 + reg];
    const float brr = b_r[0];

    // ---- LDS byte offsets (XOR swizzle on 16B slots within 128B seq-rows) ----
    const int swz = c & 7;
    const int wraddr  = c * 128 + ((((u0 >> 3)) ^ swz) << 4) + (u0 & 7) * 2;
    const int rdaddr0 = c * 128 + ((q ^ swz) << 4);          // units 8q..8q+7
    const int rdaddr1 = c * 128 + (((4 + q) ^ swz) << 4);    // units 32+8q..+7

    // ---- x stream base pointers (lane's seq = c) ----
    const size_t row = (size_t)(bid * 16 + c) * TT;
    const float* po = obs + row * DOBS;
    const float* pa = act + row * DACT;

    const short8 zero8 = {0, 0, 0, 0, 0, 0, 0, 0};
    const f32x4 zf = {0.f, 0.f, 0.f, 0.f};

    // ---- init: h(-1)=0 in hbuf[0]; prime the gi pipeline ----
    ((uint2*)hbuf[0])[tid] = make_uint2(0u, 0u);   // 256 x 8B = 2KB = hbuf[0]
    short8 xoA, xaA, xoB, xaB;
    LOADX(xoA, xaA, 0)
    LOADX(xoB, xaB, 1)
    f32x4 cgrA = MFMA(AX[0][1], xaA, MFMA(AX[0][0], xoA, zf));  // gi(0)
    f32x4 cgzA = MFMA(AX[1][1], xaA, MFMA(AX[1][0], xoA, zf));
    f32x4 cgnA = MFMA(AX[2][1], xaA, MFMA(AX[2][0], xoA, zf));
    f32x4 cgrB = MFMA(AX[0][1], xaB, MFMA(AX[0][0], xoB, zf));  // gi(1)
    f32x4 cgzB = MFMA(AX[1][1], xaB, MFMA(AX[1][0], xoB, zf));
    f32x4 cgnB = MFMA(AX[2][1], xaB, MFMA(AX[2][0], xoB, zf));
    LOADX(xoA, xaA, 2)                      // x(2), x(3) into the x ring
    LOADX(xoB, xaB, 3)
    float hold[4] = {0.f, 0.f, 0.f, 0.f};
    asm volatile("s_waitcnt lgkmcnt(0)" ::: "memory");
    __builtin_amdgcn_s_barrier();
    asm volatile("" ::: "memory");

    float* rew = out + (size_t)BB * HH;      // out: [h_final B*H][rewards B*T]

#pragma unroll 1
    for (int t = 0; t < TT; t += 2) {
        STEP(xoA, xaA, cgrA, cgzA, cgnA, 0, t)
        STEP(xoB, xaB, cgrB, cgzB, cgnB, 1, t + 1)
    }

    // ---- epilogue: reward(T-1) from h(T-1) (in hbuf[0]); h_final stores ----
    if (w == 3) {
        short8 Ah0 = *(const short8*)((const char*)hbuf[0] + rdaddr0);
        short8 Ah1 = *(const short8*)((const char*)hbuf[0] + rdaddr1);
        f32x4 Crw = MFMA(AR[0], Ah0, zf);
        Crw = MFMA(AR[1], Ah1, Crw);
        if (q == 0)
            rew[(size_t)(bid * 16 + c) * TT + TT - 1] = Crw[0] + brr;
    }
    *(float4*)(out + (size_t)(bid * 16 + c) * HH + u0) =
        make_float4(hold[0], hold[1], hold[2], hold[3]);
}

// ------------------------------------------------------------------- host ---
extern "C" void kernel_launch(void* const* d_in, const int* in_sizes, int n_in,
                              void* d_out, int out_size, void* d_ws, size_t ws_size,
                              hipStream_t stream)
{
    const float* obs    = (const float*)d_in[0];
    const float* action = (const float*)d_in[1];
    const float* W_ih   = (const float*)d_in[2];
    const float* b_ih   = (const float*)d_in[3];
    const float* W_hh   = (const float*)d_in[4];
    const float* b_hh   = (const float*)d_in[5];
    const float* W_r    = (const float*)d_in[6];
    const float* b_r    = (const float*)d_in[7];
    float* out          = (float*)d_out;

    gru_fused<<<dim3(BB / 16), dim3(256), 0, stream>>>(
        obs, action, W_ih, b_ih, W_hh, b_hh, W_r, b_r, out);
}

// Round 8
// 482.535 us; speedup vs baseline: 2.0074x; 2.0074x over previous
//
#include <hip/hip_runtime.h>

// GRU reward model: swapped-operand MFMA + packed x-stream + gi 2-step pipeline.
//   B=1024 seqs, T=1024 steps, Din=36 (obs32+act4+bias), H=64, gates 3H=192.
//   64 blocks x 256 threads (4 waves); block owns 16 sequences.
//   A = weight tiles (units in M), B = [x|h] (seqs in N); C = [units x seqs]:
//   lane owns 4 consecutive units of one seq.
//   - x stream pre-packed to bf16 by pack_x (row = [obs32, act4, 1.0, pad3]):
//     loaded fragments ARE registers (no converts) -> vmcnt waits have 2 full
//     steps of slack and never stall (round-7 lesson: converts in-step expose
//     full HBM latency serially).
//   - gi(t) computed 2 steps ahead into named f32x4 ring slots -> per-step
//     critical chain is only: bar -> ds_read h -> 2 dep h-MFMAs -> gates ->
//     packed ds_write -> bar. The 6 gi MFMAs + LOADX fill the ds_read shadow.
//   One s_barrier + lgkmcnt(0) per step; vmcnt never drains across barriers.

#define BB 1024
#define TT 1024
#define DOBS 32
#define DACT 4
#define HH 64

typedef __attribute__((ext_vector_type(8))) short short8;
typedef __attribute__((ext_vector_type(4))) float f32x4;

#define MFMA(A, B, C) __builtin_amdgcn_mfma_f32_16x16x32_bf16((A), (B), (C), 0, 0, 0)

static __device__ __forceinline__ unsigned short f2bf(float f) {
    unsigned u = __float_as_uint(f);
    u += 0x7fffu + ((u >> 16) & 1u);   // RNE
    return (unsigned short)(u >> 16);
}
static __device__ __forceinline__ float frcp(float x) { return __builtin_amdgcn_rcpf(x); }
static __device__ __forceinline__ unsigned cvt_pk(float lo, float hi) {
    unsigned r;
    asm("v_cvt_pk_bf16_f32 %0, %1, %2" : "=v"(r) : "v"(lo), "v"(hi));
    return r;
}

#define L2E 1.442695040888963f

// ---- pre-kernel: xext[(b*TT+t)*40] = bf16 [obs(32), act(4), 1.0, 0,0,0] ----
__global__ __launch_bounds__(256)
void pack_x(const float* __restrict__ obs, const float* __restrict__ act,
            unsigned short* __restrict__ xext)
{
    const size_t r = (size_t)blockIdx.x * 256 + threadIdx.x;   // (b,t) row
    const float* o = obs + r * DOBS;
    unsigned short* d = xext + r * 40;
    short8 v[5];
#pragma unroll
    for (int j = 0; j < 4; ++j) {
        float4 a = ((const float4*)o)[2 * j];
        float4 b = ((const float4*)o)[2 * j + 1];
        short8 t;
        t[0]=f2bf(a.x); t[1]=f2bf(a.y); t[2]=f2bf(a.z); t[3]=f2bf(a.w);
        t[4]=f2bf(b.x); t[5]=f2bf(b.y); t[6]=f2bf(b.z); t[7]=f2bf(b.w);
        v[j] = t;
    }
    {
        float4 a = *(const float4*)(act + r * DACT);
        short8 t;
        t[0]=f2bf(a.x); t[1]=f2bf(a.y); t[2]=f2bf(a.z); t[3]=f2bf(a.w);
        t[4]=(short)0x3f80; t[5]=0; t[6]=0; t[7]=0;   // bias slot k=36
        v[4] = t;
    }
#pragma unroll
    for (int j = 0; j < 5; ++j) ((short8*)d)[j] = v[j];
}

// LOADX: fetch x(t) B-fragments (seq = c). PACKED: pure 16B loads, no VALU.
#define LOADX(XO, XA, T)                                                       \
  {                                                                            \
    const int tc_ = (T) < TT ? (T) : TT - 1;                                   \
    if (PACKED) {                                                              \
      XO = *(const short8*)(px + (size_t)tc_ * 40 + 8 * q);                    \
      XA = (q == 0) ? *(const short8*)(px + (size_t)tc_ * 40 + 32) : zero8;    \
    } else {                                                                   \
      const float* op_ = po + (size_t)tc_ * DOBS + 8 * q;                      \
      float4 a_ = *(const float4*)op_, b_ = *(const float4*)(op_ + 4);         \
      short8 f_;                                                               \
      f_[0]=f2bf(a_.x); f_[1]=f2bf(a_.y); f_[2]=f2bf(a_.z); f_[3]=f2bf(a_.w);  \
      f_[4]=f2bf(b_.x); f_[5]=f2bf(b_.y); f_[6]=f2bf(b_.z); f_[7]=f2bf(b_.w);  \
      XO = f_;                                                                 \
      if (q == 0) {                                                            \
        float4 av_ = *(const float4*)(pa + (size_t)tc_ * DACT);                \
        short8 g_;                                                             \
        g_[0]=f2bf(av_.x); g_[1]=f2bf(av_.y); g_[2]=f2bf(av_.z);               \
        g_[3]=f2bf(av_.w); g_[4]=(short)0x3f80; g_[5]=0; g_[6]=0; g_[7]=0;     \
        XA = g_;                                                               \
      } else XA = zero8;                                                       \
    }                                                                          \
  }

// STEP: PH = literal hbuf phase. CR_/CZ_/CN_ = this parity's gi ring (named regs).
#define STEP(XO, XA, CR_, CZ_, CN_, PH, T)                                     \
  {                                                                            \
    short8 Ah0 = *(const short8*)((const char*)hbuf[PH] + rdaddr0);            \
    short8 Ah1 = *(const short8*)((const char*)hbuf[PH] + rdaddr1);            \
    f32x4 cr_ = CR_, cz_ = CZ_, cni_ = CN_;      /* gi(T), computed at T-2 */  \
    CR_ = MFMA(AX[0][1], XA, MFMA(AX[0][0], XO, zf));   /* gi(T+2): off-chain */ \
    CZ_ = MFMA(AX[1][1], XA, MFMA(AX[1][0], XO, zf));                          \
    CN_ = MFMA(AX[2][1], XA, MFMA(AX[2][0], XO, zf));                          \
    LOADX(XO, XA, (T) + 4)                       /* refill x ring (t+4) */     \
    f32x4 Cr  = MFMA(AH[0][1], Ah1, MFMA(AH[0][0], Ah0, cr_));                 \
    f32x4 Cz  = MFMA(AH[1][1], Ah1, MFMA(AH[1][0], Ah0, cz_));                 \
    f32x4 Cnh = MFMA(AH[2][1], Ah1, MFMA(AH[2][0], Ah0, bhn4));                \
    f32x4 Crw = zf;                                                            \
    if (w == 3) Crw = MFMA(AR[1], Ah1, MFMA(AR[0], Ah0, zf));                  \
    _Pragma("unroll")                                                          \
    for (int reg = 0; reg < 4; ++reg) {                                        \
      float rr   = frcp(1.0f + __builtin_amdgcn_exp2f(Cr[reg] * -L2E));        \
      float zz   = frcp(1.0f + __builtin_amdgcn_exp2f(Cz[reg] * -L2E));        \
      float npre = __builtin_fmaf(rr, Cnh[reg], cni_[reg]);                    \
      float nn   = 1.0f - 2.0f * frcp(__builtin_amdgcn_exp2f(npre * (2.0f * L2E)) + 1.0f); \
      hold[reg]  = __builtin_fmaf(zz, hold[reg] - nn, nn);                     \
    }                                                                          \
    unsigned pk0 = cvt_pk(hold[0], hold[1]);                                   \
    unsigned pk1 = cvt_pk(hold[2], hold[3]);                                   \
    *(uint2*)((char*)hbuf[PH ^ 1] + wraddr) = make_uint2(pk0, pk1);            \
    if (w == 3 && q == 0 && (T) > 0)                                           \
      rew[(size_t)(bid * 16 + c) * TT + (T) - 1] = Crw[0] + brr;               \
    asm volatile("s_waitcnt lgkmcnt(0)" ::: "memory");                         \
    __builtin_amdgcn_s_barrier();                                              \
    asm volatile("" ::: "memory");                                             \
  }

template<bool PACKED>
__global__ __launch_bounds__(256, 1)
void gru_fused(const unsigned short* __restrict__ xext,
               const float* __restrict__ obs, const float* __restrict__ act,
               const float* __restrict__ W_ih, const float* __restrict__ b_ih,
               const float* __restrict__ W_hh, const float* __restrict__ b_hh,
               const float* __restrict__ W_r, const float* __restrict__ b_r,
               float* __restrict__ out)
{
    const int tid = threadIdx.x;
    const int w = tid >> 6, l = tid & 63, c = l & 15, q = l >> 4;
    const int bid = blockIdx.x;
    const int u0 = 16 * w + 4 * q;           // first of this lane's 4 units

    __shared__ __align__(16) unsigned short hbuf[2][16 * 64];  // [seq][unit] bf16

    // ---- weight A-fragments ----
    short8 AX[3][2], AH[3][2];
#pragma unroll
    for (int m = 0; m < 3; ++m) {
        const int j = w + 4 * m;             // tile: w=r, w+4=z, w+8=n
        const int g = 16 * j + c;            // gate row (A-row = c)
        {   // x-weights, k 0..31
            const float* wp = W_ih + (size_t)g * 36 + 8 * q;
            float4 a = *(const float4*)wp, b = *(const float4*)(wp + 4);
            short8 f;
            f[0]=f2bf(a.x); f[1]=f2bf(a.y); f[2]=f2bf(a.z); f[3]=f2bf(a.w);
            f[4]=f2bf(b.x); f[5]=f2bf(b.y); f[6]=f2bf(b.z); f[7]=f2bf(b.w);
            AX[m][0] = f;
        }
        {   // x-weights, k 32..63 (act + bias slot + zeros)
            short8 f;
#pragma unroll
            for (int i = 0; i < 8; ++i) {
                int k = 32 + 8 * q + i;
                float v = 0.f;
                if (k < 36)       v = W_ih[(size_t)g * 36 + k];
                else if (k == 36) v = b_ih[g] + (g < 128 ? b_hh[g] : 0.f);
                f[i] = f2bf(v);
            }
            AX[m][1] = f;
        }
#pragma unroll
        for (int kk = 0; kk < 2; ++kk) {     // h-weights
            const float* wp = W_hh + (size_t)g * HH + 32 * kk + 8 * q;
            float4 a = *(const float4*)wp, b = *(const float4*)(wp + 4);
            short8 f;
            f[0]=f2bf(a.x); f[1]=f2bf(a.y); f[2]=f2bf(a.z); f[3]=f2bf(a.w);
            f[4]=f2bf(b.x); f[5]=f2bf(b.y); f[6]=f2bf(b.z); f[7]=f2bf(b.w);
            AH[m][kk] = f;
        }
    }
    short8 AR[2];                            // reward tile: A-row 0 = W_r
#pragma unroll
    for (int kk = 0; kk < 2; ++kk) {
        short8 f;
#pragma unroll
        for (int i = 0; i < 8; ++i) {
            int k = 32 * kk + 8 * q + i;
            f[i] = (c == 0) ? (short)f2bf(W_r[k]) : (short)0;
        }
        AR[kk] = f;
    }

    f32x4 bhn4;                              // Cnh C-init: b_hh[n] for lane's units
#pragma unroll
    for (int reg = 0; reg < 4; ++reg) bhn4[reg] = b_hh[128 + u0 + reg];
    const float brr = b_r[0];

    // ---- LDS byte offsets (XOR swizzle on 16B slots within 128B seq-rows) ----
    const int swz = c & 7;
    const int wraddr  = c * 128 + ((((u0 >> 3)) ^ swz) << 4) + (u0 & 7) * 2;
    const int rdaddr0 = c * 128 + ((q ^ swz) << 4);          // units 8q..8q+7
    const int rdaddr1 = c * 128 + (((4 + q) ^ swz) << 4);    // units 32+8q..+7

    // ---- x stream base pointers (lane's seq = c) ----
    const size_t row = (size_t)(bid * 16 + c) * TT;
    const unsigned short* px = xext + row * 40;
    const float* po = obs + row * DOBS;
    const float* pa = act + row * DACT;

    const short8 zero8 = {0, 0, 0, 0, 0, 0, 0, 0};
    const f32x4 zf = {0.f, 0.f, 0.f, 0.f};

    // ---- init: h(-1)=0 in hbuf[0]; prime the x ring + gi pipeline ----
    ((uint2*)hbuf[0])[tid] = make_uint2(0u, 0u);   // 256 x 8B = 2KB = hbuf[0]
    short8 xoA, xaA, xoB, xaB;
    LOADX(xoA, xaA, 0)
    LOADX(xoB, xaB, 1)
    f32x4 cgrA = MFMA(AX[0][1], xaA, MFMA(AX[0][0], xoA, zf));  // gi(0)
    f32x4 cgzA = MFMA(AX[1][1], xaA, MFMA(AX[1][0], xoA, zf));
    f32x4 cgnA = MFMA(AX[2][1], xaA, MFMA(AX[2][0], xoA, zf));
    f32x4 cgrB = MFMA(AX[0][1], xaB, MFMA(AX[0][0], xoB, zf));  // gi(1)
    f32x4 cgzB = MFMA(AX[1][1], xaB, MFMA(AX[1][0], xoB, zf));
    f32x4 cgnB = MFMA(AX[2][1], xaB, MFMA(AX[2][0], xoB, zf));
    LOADX(xoA, xaA, 2)                      // x(2), x(3) into the x ring
    LOADX(xoB, xaB, 3)
    float hold[4] = {0.f, 0.f, 0.f, 0.f};
    asm volatile("s_waitcnt lgkmcnt(0)" ::: "memory");
    __builtin_amdgcn_s_barrier();
    asm volatile("" ::: "memory");

    float* rew = out + (size_t)BB * HH;      // out: [h_final B*H][rewards B*T]

#pragma unroll 1
    for (int t = 0; t < TT; t += 2) {
        STEP(xoA, xaA, cgrA, cgzA, cgnA, 0, t)
        STEP(xoB, xaB, cgrB, cgzB, cgnB, 1, t + 1)
    }

    // ---- epilogue: reward(T-1) from h(T-1) (in hbuf[0]); h_final stores ----
    if (w == 3) {
        short8 Ah0 = *(const short8*)((const char*)hbuf[0] + rdaddr0);
        short8 Ah1 = *(const short8*)((const char*)hbuf[0] + rdaddr1);
        f32x4 Crw = MFMA(AR[0], Ah0, zf);
        Crw = MFMA(AR[1], Ah1, Crw);
        if (q == 0)
            rew[(size_t)(bid * 16 + c) * TT + TT - 1] = Crw[0] + brr;
    }
    *(float4*)(out + (size_t)(bid * 16 + c) * HH + u0) =
        make_float4(hold[0], hold[1], hold[2], hold[3]);
}

// ------------------------------------------------------------------- host ---
extern "C" void kernel_launch(void* const* d_in, const int* in_sizes, int n_in,
                              void* d_out, int out_size, void* d_ws, size_t ws_size,
                              hipStream_t stream)
{
    const float* obs    = (const float*)d_in[0];
    const float* action = (const float*)d_in[1];
    const float* W_ih   = (const float*)d_in[2];
    const float* b_ih   = (const float*)d_in[3];
    const float* W_hh   = (const float*)d_in[4];
    const float* b_hh   = (const float*)d_in[5];
    const float* W_r    = (const float*)d_in[6];
    const float* b_r    = (const float*)d_in[7];
    float* out          = (float*)d_out;

    const size_t xext_bytes = (size_t)BB * TT * 40 * sizeof(unsigned short); // 80 MB
    if (ws_size >= xext_bytes) {
        unsigned short* xext = (unsigned short*)d_ws;
        pack_x<<<dim3((BB * TT) / 256), dim3(256), 0, stream>>>(obs, action, xext);
        gru_fused<true><<<dim3(BB / 16), dim3(256), 0, stream>>>(
            xext, obs, action, W_ih, b_ih, W_hh, b_hh, W_r, b_r, out);
    } else {
        gru_fused<false><<<dim3(BB / 16), dim3(256), 0, stream>>>(
            nullptr, obs, action, W_ih, b_ih, W_hh, b_hh, W_r, b_r, out);
    }
}

// Round 9
// 415.269 us; speedup vs baseline: 2.3325x; 1.1620x over previous
//
#include <hip/hip_runtime.h>

// GRU reward model: swapped-operand MFMA + packed x-stream + gi 2-step pipeline
// + ISSUE-TRIMMED gates (round 9).
//   B=1024 seqs, T=1024 steps, Din=36 (obs32+act4+bias), H=64, gates 3H=192.
//   64 blocks x 256 threads (4 waves); block owns 16 sequences.
//   A = weight tiles (units in M), B = [x|h] (seqs in N); C = [units x seqs].
//   Round-8 postmortem: kernel is instruction-ISSUE-limited (~9 cyc/instr at
//   1 wave/SIMD; r5->r6 evidence). So this round removes instructions:
//    - exp2 argument scaling folded into the WEIGHTS at fragment-load time:
//      r,z rows scaled by -log2(e); n rows by +2*log2(e). Gates: 13 instr/reg.
//    - LOADX clamp dropped (xext carries 4 slack rows in ws; tail-step loads
//      feed only discarded gi values).
//    - 4-step unroll.

#define BB 1024
#define TT 1024
#define DOBS 32
#define DACT 4
#define HH 64

typedef __attribute__((ext_vector_type(8))) short short8;
typedef __attribute__((ext_vector_type(4))) float f32x4;

#define MFMA(A, B, C) __builtin_amdgcn_mfma_f32_16x16x32_bf16((A), (B), (C), 0, 0, 0)

static __device__ __forceinline__ unsigned short f2bf(float f) {
    unsigned u = __float_as_uint(f);
    u += 0x7fffu + ((u >> 16) & 1u);   // RNE
    return (unsigned short)(u >> 16);
}
static __device__ __forceinline__ float frcp(float x) { return __builtin_amdgcn_rcpf(x); }
static __device__ __forceinline__ unsigned cvt_pk(float lo, float hi) {
    unsigned r;
    asm("v_cvt_pk_bf16_f32 %0, %1, %2" : "=v"(r) : "v"(lo), "v"(hi));
    return r;
}

#define L2E 1.442695040888963f

// ---- pre-kernel: xext[(b*TT+t)*40] = bf16 [obs(32), act(4), 1.0, 0,0,0] ----
__global__ __launch_bounds__(256)
void pack_x(const float* __restrict__ obs, const float* __restrict__ act,
            unsigned short* __restrict__ xext)
{
    const size_t r = (size_t)blockIdx.x * 256 + threadIdx.x;   // (b,t) row
    const float* o = obs + r * DOBS;
    unsigned short* d = xext + r * 40;
    short8 v[5];
#pragma unroll
    for (int j = 0; j < 4; ++j) {
        float4 a = ((const float4*)o)[2 * j];
        float4 b = ((const float4*)o)[2 * j + 1];
        short8 t;
        t[0]=f2bf(a.x); t[1]=f2bf(a.y); t[2]=f2bf(a.z); t[3]=f2bf(a.w);
        t[4]=f2bf(b.x); t[5]=f2bf(b.y); t[6]=f2bf(b.z); t[7]=f2bf(b.w);
        v[j] = t;
    }
    {
        float4 a = *(const float4*)(act + r * DACT);
        short8 t;
        t[0]=f2bf(a.x); t[1]=f2bf(a.y); t[2]=f2bf(a.z); t[3]=f2bf(a.w);
        t[4]=(short)0x3f80; t[5]=0; t[6]=0; t[7]=0;   // bias slot k=36
        v[4] = t;
    }
#pragma unroll
    for (int j = 0; j < 5; ++j) ((short8*)d)[j] = v[j];
}

// LOADX: fetch x(t) B-fragments (seq = c). PACKED: no clamp (ws slack rows).
#define LOADX(XO, XA, T)                                                       \
  {                                                                            \
    if (PACKED) {                                                              \
      XO = *(const short8*)(px + (size_t)(T) * 40 + 8 * q);                    \
      XA = (q == 0) ? *(const short8*)(px + (size_t)(T) * 40 + 32) : zero8;    \
    } else {                                                                   \
      const int tc_ = (T) < TT ? (T) : TT - 1;                                 \
      const float* op_ = po + (size_t)tc_ * DOBS + 8 * q;                      \
      float4 a_ = *(const float4*)op_, b_ = *(const float4*)(op_ + 4);         \
      short8 f_;                                                               \
      f_[0]=f2bf(a_.x); f_[1]=f2bf(a_.y); f_[2]=f2bf(a_.z); f_[3]=f2bf(a_.w);  \
      f_[4]=f2bf(b_.x); f_[5]=f2bf(b_.y); f_[6]=f2bf(b_.z); f_[7]=f2bf(b_.w);  \
      XO = f_;                                                                 \
      if (q == 0) {                                                            \
        float4 av_ = *(const float4*)(pa + (size_t)tc_ * DACT);                \
        short8 g_;                                                             \
        g_[0]=f2bf(av_.x); g_[1]=f2bf(av_.y); g_[2]=f2bf(av_.z);               \
        g_[3]=f2bf(av_.w); g_[4]=(short)0x3f80; g_[5]=0; g_[6]=0; g_[7]=0;     \
        XA = g_;                                                               \
      } else XA = zero8;                                                       \
    }                                                                          \
  }

// STEP: PH = literal hbuf phase. CR_/CZ_/CN_ = this parity's gi ring (named).
// Weights pre-scaled: Cr,Cz = -L2E * preact; Cni,Cnh = 2*L2E * preact parts.
#define STEP(XO, XA, CR_, CZ_, CN_, PH, T)                                     \
  {                                                                            \
    short8 Ah0 = *(const short8*)((const char*)hbuf[PH] + rdaddr0);            \
    short8 Ah1 = *(const short8*)((const char*)hbuf[PH] + rdaddr1);            \
    f32x4 cr_ = CR_, cz_ = CZ_, cni_ = CN_;      /* gi(T), computed at T-2 */  \
    CR_ = MFMA(AX[0][1], XA, MFMA(AX[0][0], XO, zf));   /* gi(T+2): off-chain */ \
    CZ_ = MFMA(AX[1][1], XA, MFMA(AX[1][0], XO, zf));                          \
    CN_ = MFMA(AX[2][1], XA, MFMA(AX[2][0], XO, zf));                          \
    LOADX(XO, XA, (T) + 4)                       /* refill x ring (t+4) */     \
    f32x4 Cr  = MFMA(AH[0][1], Ah1, MFMA(AH[0][0], Ah0, cr_));                 \
    f32x4 Cz  = MFMA(AH[1][1], Ah1, MFMA(AH[1][0], Ah0, cz_));                 \
    f32x4 Cnh = MFMA(AH[2][1], Ah1, MFMA(AH[2][0], Ah0, bhn4));                \
    f32x4 Crw = zf;                                                            \
    if (w == 3) Crw = MFMA(AR[1], Ah1, MFMA(AR[0], Ah0, zf));                  \
    _Pragma("unroll")                                                          \
    for (int reg = 0; reg < 4; ++reg) {                                        \
      float rr   = frcp(1.0f + __builtin_amdgcn_exp2f(Cr[reg]));               \
      float zz   = frcp(1.0f + __builtin_amdgcn_exp2f(Cz[reg]));               \
      float E    = __builtin_amdgcn_exp2f(__builtin_fmaf(rr, Cnh[reg], cni_[reg])); \
      float nn   = __builtin_fmaf(-2.0f, frcp(E + 1.0f), 1.0f);                \
      hold[reg]  = __builtin_fmaf(zz, hold[reg] - nn, nn);                     \
    }                                                                          \
    unsigned pk0 = cvt_pk(hold[0], hold[1]);                                   \
    unsigned pk1 = cvt_pk(hold[2], hold[3]);                                   \
    *(uint2*)((char*)hbuf[PH ^ 1] + wraddr) = make_uint2(pk0, pk1);            \
    if (w == 3 && q == 0 && (T) > 0)                                           \
      rew[(size_t)(bid * 16 + c) * TT + (T) - 1] = Crw[0] + brr;               \
    asm volatile("s_waitcnt lgkmcnt(0)" ::: "memory");                         \
    __builtin_amdgcn_s_barrier();                                              \
    asm volatile("" ::: "memory");                                             \
  }

template<bool PACKED>
__global__ __launch_bounds__(256, 1)
void gru_fused(const unsigned short* __restrict__ xext,
               const float* __restrict__ obs, const float* __restrict__ act,
               const float* __restrict__ W_ih, const float* __restrict__ b_ih,
               const float* __restrict__ W_hh, const float* __restrict__ b_hh,
               const float* __restrict__ W_r, const float* __restrict__ b_r,
               float* __restrict__ out)
{
    const int tid = threadIdx.x;
    const int w = tid >> 6, l = tid & 63, c = l & 15, q = l >> 4;
    const int bid = blockIdx.x;
    const int u0 = 16 * w + 4 * q;           // first of this lane's 4 units

    __shared__ __align__(16) unsigned short hbuf[2][16 * 64];  // [seq][unit] bf16

    // ---- weight A-fragments, PRE-SCALED for the gate exp2s ----
    //   m=0 (r), m=1 (z): rows * -L2E;  m=2 (n): rows * +2*L2E.
    short8 AX[3][2], AH[3][2];
#pragma unroll
    for (int m = 0; m < 3; ++m) {
        const float sc = (m == 2) ? (2.0f * L2E) : (-L2E);
        const int j = w + 4 * m;             // tile: w=r, w+4=z, w+8=n
        const int g = 16 * j + c;            // gate row (A-row = c)
        {   // x-weights, k 0..31
            const float* wp = W_ih + (size_t)g * 36 + 8 * q;
            float4 a = *(const float4*)wp, b = *(const float4*)(wp + 4);
            short8 f;
            f[0]=f2bf(a.x*sc); f[1]=f2bf(a.y*sc); f[2]=f2bf(a.z*sc); f[3]=f2bf(a.w*sc);
            f[4]=f2bf(b.x*sc); f[5]=f2bf(b.y*sc); f[6]=f2bf(b.z*sc); f[7]=f2bf(b.w*sc);
            AX[m][0] = f;
        }
        {   // x-weights, k 32..63 (act + bias slot + zeros)
            short8 f;
#pragma unroll
            for (int i = 0; i < 8; ++i) {
                int k = 32 + 8 * q + i;
                float v = 0.f;
                if (k < 36)       v = W_ih[(size_t)g * 36 + k];
                else if (k == 36) v = b_ih[g] + (g < 128 ? b_hh[g] : 0.f);
                f[i] = f2bf(v * sc);
            }
            AX[m][1] = f;
        }
#pragma unroll
        for (int kk = 0; kk < 2; ++kk) {     // h-weights
            const float* wp = W_hh + (size_t)g * HH + 32 * kk + 8 * q;
            float4 a = *(const float4*)wp, b = *(const float4*)(wp + 4);
            short8 f;
            f[0]=f2bf(a.x*sc); f[1]=f2bf(a.y*sc); f[2]=f2bf(a.z*sc); f[3]=f2bf(a.w*sc);
            f[4]=f2bf(b.x*sc); f[5]=f2bf(b.y*sc); f[6]=f2bf(b.z*sc); f[7]=f2bf(b.w*sc);
            AH[m][kk] = f;
        }
    }
    short8 AR[2];                            // reward tile: A-row 0 = W_r (unscaled)
#pragma unroll
    for (int kk = 0; kk < 2; ++kk) {
        short8 f;
#pragma unroll
        for (int i = 0; i < 8; ++i) {
            int k = 32 * kk + 8 * q + i;
            f[i] = (c == 0) ? (short)f2bf(W_r[k]) : (short)0;
        }
        AR[kk] = f;
    }

    f32x4 bhn4;                              // Cnh C-init: 2*L2E * b_hh[n-rows]
#pragma unroll
    for (int reg = 0; reg < 4; ++reg) bhn4[reg] = b_hh[128 + u0 + reg] * (2.0f * L2E);
    const float brr = b_r[0];

    // ---- LDS byte offsets (XOR swizzle on 16B slots within 128B seq-rows) ----
    const int swz = c & 7;
    const int wraddr  = c * 128 + ((((u0 >> 3)) ^ swz) << 4) + (u0 & 7) * 2;
    const int rdaddr0 = c * 128 + ((q ^ swz) << 4);          // units 8q..8q+7
    const int rdaddr1 = c * 128 + (((4 + q) ^ swz) << 4);    // units 32+8q..+7

    // ---- x stream base pointers (lane's seq = c) ----
    const size_t row = (size_t)(bid * 16 + c) * TT;
    const unsigned short* px = xext + row * 40;
    const float* po = obs + row * DOBS;
    const float* pa = act + row * DACT;

    const short8 zero8 = {0, 0, 0, 0, 0, 0, 0, 0};
    const f32x4 zf = {0.f, 0.f, 0.f, 0.f};

    // ---- init: h(-1)=0 in hbuf[0]; prime the x ring + gi pipeline ----
    ((uint2*)hbuf[0])[tid] = make_uint2(0u, 0u);   // 256 x 8B = 2KB = hbuf[0]
    short8 xoA, xaA, xoB, xaB;
    LOADX(xoA, xaA, 0)
    LOADX(xoB, xaB, 1)
    f32x4 cgrA = MFMA(AX[0][1], xaA, MFMA(AX[0][0], xoA, zf));  // gi(0)
    f32x4 cgzA = MFMA(AX[1][1], xaA, MFMA(AX[1][0], xoA, zf));
    f32x4 cgnA = MFMA(AX[2][1], xaA, MFMA(AX[2][0], xoA, zf));
    f32x4 cgrB = MFMA(AX[0][1], xaB, MFMA(AX[0][0], xoB, zf));  // gi(1)
    f32x4 cgzB = MFMA(AX[1][1], xaB, MFMA(AX[1][0], xoB, zf));
    f32x4 cgnB = MFMA(AX[2][1], xaB, MFMA(AX[2][0], xoB, zf));
    LOADX(xoA, xaA, 2)                      // x(2), x(3) into the x ring
    LOADX(xoB, xaB, 3)
    float hold[4] = {0.f, 0.f, 0.f, 0.f};
    asm volatile("s_waitcnt lgkmcnt(0)" ::: "memory");
    __builtin_amdgcn_s_barrier();
    asm volatile("" ::: "memory");

    float* rew = out + (size_t)BB * HH;      // out: [h_final B*H][rewards B*T]

#pragma unroll 1
    for (int t = 0; t < TT; t += 4) {
        STEP(xoA, xaA, cgrA, cgzA, cgnA, 0, t)
        STEP(xoB, xaB, cgrB, cgzB, cgnB, 1, t + 1)
        STEP(xoA, xaA, cgrA, cgzA, cgnA, 0, t + 2)
        STEP(xoB, xaB, cgrB, cgzB, cgnB, 1, t + 3)
    }

    // ---- epilogue: reward(T-1) from h(T-1) (in hbuf[0]); h_final stores ----
    if (w == 3) {
        short8 Ah0 = *(const short8*)((const char*)hbuf[0] + rdaddr0);
        short8 Ah1 = *(const short8*)((const char*)hbuf[0] + rdaddr1);
        f32x4 Crw = MFMA(AR[0], Ah0, zf);
        Crw = MFMA(AR[1], Ah1, Crw);
        if (q == 0)
            rew[(size_t)(bid * 16 + c) * TT + TT - 1] = Crw[0] + brr;
    }
    *(float4*)(out + (size_t)(bid * 16 + c) * HH + u0) =
        make_float4(hold[0], hold[1], hold[2], hold[3]);
}

// ------------------------------------------------------------------- host ---
extern "C" void kernel_launch(void* const* d_in, const int* in_sizes, int n_in,
                              void* d_out, int out_size, void* d_ws, size_t ws_size,
                              hipStream_t stream)
{
    const float* obs    = (const float*)d_in[0];
    const float* action = (const float*)d_in[1];
    const float* W_ih   = (const float*)d_in[2];
    const float* b_ih   = (const float*)d_in[3];
    const float* W_hh   = (const float*)d_in[4];
    const float* b_hh   = (const float*)d_in[5];
    const float* W_r    = (const float*)d_in[6];
    const float* b_r    = (const float*)d_in[7];
    float* out          = (float*)d_out;

    // xext (80 MB) + 4 slack rows so the unclamped t+4 prefetch stays in ws.
    const size_t xext_bytes = ((size_t)BB * TT + 8) * 40 * sizeof(unsigned short);
    if (ws_size >= xext_bytes) {
        unsigned short* xext = (unsigned short*)d_ws;
        pack_x<<<dim3((BB * TT) / 256), dim3(256), 0, stream>>>(obs, action, xext);
        gru_fused<true><<<dim3(BB / 16), dim3(256), 0, stream>>>(
            xext, obs, action, W_ih, b_ih, W_hh, b_hh, W_r, b_r, out);
    } else {
        gru_fused<false><<<dim3(BB / 16), dim3(256), 0, stream>>>(
            nullptr, obs, action, W_ih, b_ih, W_hh, b_hh, W_r, b_r, out);
    }
}